// Round 2
// baseline (29118.668 us; speedup 1.0000x reference)
//
#include <hip/hip_runtime.h>
#include <math.h>

#define NN_  10000
#define NE_  320000
#define IND  64
#define HID  128
#define G3   384   // 3*HID
#define HC1  512   // 4 heads * 128
#define OUTD 64

__device__ __forceinline__ float sigmoidf_(float x){ return 1.f/(1.f+expf(-x)); }
__device__ __forceinline__ float leakyf_(float x){ return x>0.f ? x : 0.2f*x; }

// ---------------------------------------------------------------------------
// Generic tiled fp32 GEMM.  C[m,n] = sum_k A[m,k] * (TB ? B[n,k] : B[k,n]) + bias[n]
// Requires: N % 64 == 0, K % 16 == 0 (true for all uses). M guarded.
// ---------------------------------------------------------------------------
template<bool TB>
__global__ __launch_bounds__(256) void gemm_k(const float* __restrict__ A,
                                              const float* __restrict__ B,
                                              const float* __restrict__ bias,
                                              float* __restrict__ C,
                                              int M, int N, int K) {
  __shared__ float As[16][65];
  __shared__ float Bs[16][65];
  const int bm = blockIdx.x * 64, bn = blockIdx.y * 64;
  const int tid = threadIdx.x;
  const int tm = (tid >> 4) << 2, tn = (tid & 15) << 2;
  float acc[4][4] = {};
  const int row = tid & 63, kq = (tid >> 6) << 2;
  for (int k0 = 0; k0 < K; k0 += 16) {
    // A tile: 64 rows x 16 k
    float4 av = make_float4(0.f, 0.f, 0.f, 0.f);
    const int m = bm + row;
    if (m < M) av = *(const float4*)(A + (size_t)m * K + k0 + kq);
    As[kq + 0][row] = av.x; As[kq + 1][row] = av.y;
    As[kq + 2][row] = av.z; As[kq + 3][row] = av.w;
    if (TB) {
      float4 bv = *(const float4*)(B + (size_t)(bn + row) * K + k0 + kq);
      Bs[kq + 0][row] = bv.x; Bs[kq + 1][row] = bv.y;
      Bs[kq + 2][row] = bv.z; Bs[kq + 3][row] = bv.w;
    } else {
      const int kr = tid >> 4, nq = (tid & 15) << 2;
      float4 bv = *(const float4*)(B + (size_t)(k0 + kr) * N + bn + nq);
      Bs[kr][nq + 0] = bv.x; Bs[kr][nq + 1] = bv.y;
      Bs[kr][nq + 2] = bv.z; Bs[kr][nq + 3] = bv.w;
    }
    __syncthreads();
#pragma unroll
    for (int kk = 0; kk < 16; kk++) {
      float a[4], b[4];
#pragma unroll
      for (int i = 0; i < 4; i++) a[i] = As[kk][tm + i];
#pragma unroll
      for (int j = 0; j < 4; j++) b[j] = Bs[kk][tn + j];
#pragma unroll
      for (int i = 0; i < 4; i++)
#pragma unroll
        for (int j = 0; j < 4; j++) acc[i][j] = fmaf(a[i], b[j], acc[i][j]);
    }
    __syncthreads();
  }
#pragma unroll
  for (int i = 0; i < 4; i++) {
    const int m = bm + tm + i;
    if (m < M) {
#pragma unroll
      for (int j = 0; j < 4; j++) {
        const int n = bn + tn + j;
        float v = acc[i][j];
        if (bias) v += bias[n];
        C[(size_t)m * N + n] = v;
      }
    }
  }
}

// ---------------------------------------------------------------------------
// GRU scan, one layer.  Single block, 384 threads.  Thread j owns row j of
// w_hh ([384,128]) in registers.  h kept in LDS; gates computed by threads<128.
// gi = precomputed input projections [T, 384] (order r,z,n), incl. b_ih.
// ---------------------------------------------------------------------------
__global__ __launch_bounds__(384, 1) void gru_scan(const float* __restrict__ gi,
                                                   const float* __restrict__ w_hh,
                                                   const float* __restrict__ b_hh,
                                                   float* __restrict__ h_out,
                                                   int T) {
  __shared__ float h[HID];
  __shared__ float gh[G3];
  const int j = threadIdx.x;
  float w[HID];
  {
    const float* wr = w_hh + (size_t)j * HID;
#pragma unroll
    for (int k = 0; k < HID; k += 4) {
      float4 v = *(const float4*)(wr + k);
      w[k] = v.x; w[k + 1] = v.y; w[k + 2] = v.z; w[k + 3] = v.w;
    }
  }
  const float bh = b_hh[j];
  if (j < HID) h[j] = 0.f;
  __syncthreads();

  for (int t = 0; t < T; t++) {
    // issue gi loads early (consumed after the matvec -> latency hidden)
    float ir = 0.f, iz = 0.f, in_ = 0.f;
    if (j < HID) {
      const float* g = gi + (size_t)t * G3;
      ir = g[j]; iz = g[j + HID]; in_ = g[j + 2 * HID];
    }
    // matvec: gh[j] = w_hh[j,:] . h + b_hh[j]   (4 accumulators for ILP)
    float a0 = bh, a1 = 0.f, a2 = 0.f, a3 = 0.f;
#pragma unroll
    for (int k = 0; k < HID; k += 16) {
      float4 h0 = *(const float4*)(h + k);
      float4 h1 = *(const float4*)(h + k + 4);
      float4 h2 = *(const float4*)(h + k + 8);
      float4 h3 = *(const float4*)(h + k + 12);
      a0 = fmaf(w[k + 0], h0.x, a0); a0 = fmaf(w[k + 1], h0.y, a0);
      a0 = fmaf(w[k + 2], h0.z, a0); a0 = fmaf(w[k + 3], h0.w, a0);
      a1 = fmaf(w[k + 4], h1.x, a1); a1 = fmaf(w[k + 5], h1.y, a1);
      a1 = fmaf(w[k + 6], h1.z, a1); a1 = fmaf(w[k + 7], h1.w, a1);
      a2 = fmaf(w[k + 8], h2.x, a2); a2 = fmaf(w[k + 9], h2.y, a2);
      a2 = fmaf(w[k + 10], h2.z, a2); a2 = fmaf(w[k + 11], h2.w, a2);
      a3 = fmaf(w[k + 12], h3.x, a3); a3 = fmaf(w[k + 13], h3.y, a3);
      a3 = fmaf(w[k + 14], h3.z, a3); a3 = fmaf(w[k + 15], h3.w, a3);
    }
    gh[j] = (a0 + a1) + (a2 + a3);
    __syncthreads();
    if (j < HID) {
      const float r = sigmoidf_(ir + gh[j]);
      const float z = sigmoidf_(iz + gh[j + HID]);
      const float n = tanhf(in_ + r * gh[j + 2 * HID]);
      const float hn = (1.f - z) * n + z * h[j];
      h[j] = hn;
      h_out[(size_t)t * HID + j] = hn;
    }
    __syncthreads();
  }
}

// ---------------------------------------------------------------------------
// Attention per-node dots: a_s[n,h] = feat[n,h,:].att_src[h,:]  (same for dst)
// block = heads*64 threads, one node per block
// ---------------------------------------------------------------------------
__global__ void att_dots(const float* __restrict__ feat,
                         const float* __restrict__ att_src,
                         const float* __restrict__ att_dst,
                         float* __restrict__ a_s, float* __restrict__ a_d,
                         int heads, int C) {
  const int n = blockIdx.x;
  const int h = threadIdx.x >> 6;
  const int lane = threadIdx.x & 63;
  float ss = 0.f, dd = 0.f;
  const float* f = feat + (size_t)n * heads * C + h * C;
  for (int c = lane; c < C; c += 64) {
    const float v = f[c];
    ss = fmaf(v, att_src[h * C + c], ss);
    dd = fmaf(v, att_dst[h * C + c], dd);
  }
#pragma unroll
  for (int o = 32; o > 0; o >>= 1) {
    ss += __shfl_down(ss, o);
    dd += __shfl_down(dd, o);
  }
  if (lane == 0) { a_s[n * heads + h] = ss; a_d[n * heads + h] = dd; }
}

// ---------------------------------------------------------------------------
// CSR build (edge_index is int32: ei[0..E) = src, ei[E..2E) = dst)
// ---------------------------------------------------------------------------
__global__ void edge_count(const int* __restrict__ ei, int* __restrict__ cnt, int E) {
  const int e = blockIdx.x * 256 + threadIdx.x;
  if (e < E) atomicAdd(&cnt[ei[E + e]], 1);
}

__global__ __launch_bounds__(1024) void prefix_scan(const int* __restrict__ cnt,
                                                    int* __restrict__ offs,
                                                    int* __restrict__ cursor, int N) {
  __shared__ int buf[1024];
  __shared__ int carry;
  const int tid = threadIdx.x;
  if (tid == 0) carry = 0;
  __syncthreads();
  for (int base = 0; base < N; base += 1024) {
    const int i = base + tid;
    const int v = (i < N) ? cnt[i] : 0;
    buf[tid] = v;
    __syncthreads();
    for (int d = 1; d < 1024; d <<= 1) {
      int t = 0;
      if (tid >= d) t = buf[tid - d];
      __syncthreads();
      buf[tid] += t;
      __syncthreads();
    }
    const int incl = buf[tid] + carry;
    if (i < N) { offs[i] = incl - v; cursor[i] = incl - v; }
    __syncthreads();
    if (tid == 1023) carry = incl;
    __syncthreads();
  }
  if (tid == 0) offs[N] = carry;
}

__global__ void edge_fill(const int* __restrict__ ei, int* __restrict__ cursor,
                          int* __restrict__ csr, int E) {
  const int e = blockIdx.x * 256 + threadIdx.x;
  if (e < E) {
    const int d = ei[E + e];
    const int s = ei[e];
    const int pos = atomicAdd(&cursor[d], 1);
    csr[pos] = s;
  }
}

// ---------------------------------------------------------------------------
// GAT softmax-aggregation.  One block per dst node; blockDim = heads<<cshift.
// Matches reference: self-loop included, segment max, exp, normalize.
// ---------------------------------------------------------------------------
__global__ void gat_agg(const float* __restrict__ feat,
                        const float* __restrict__ a_s, const float* __restrict__ a_d,
                        const int* __restrict__ offs, const int* __restrict__ csr,
                        const float* __restrict__ bias, float* __restrict__ out,
                        int heads, int cshift, int do_relu) {
  const int n = blockIdx.x;
  const int t = threadIdx.x;
  const int HC = blockDim.x;
  const int h = t >> cshift;
  const int beg = offs[n], end = offs[n + 1];
  const float ad = a_d[n * heads + h];
  const float self_e = leakyf_(a_s[n * heads + h] + ad);
  // pass 1: max
  float m = self_e;
  for (int i = beg; i < end; i++) {
    const int s = csr[i];
    m = fmaxf(m, leakyf_(a_s[s * heads + h] + ad));
  }
  // pass 2: exp-sum + weighted gather
  float den = expf(self_e - m);
  float acc = den * feat[(size_t)n * HC + t];
  for (int i = beg; i < end; i++) {
    const int s = csr[i];
    const float wgt = expf(leakyf_(a_s[s * heads + h] + ad) - m);
    den += wgt;
    acc = fmaf(wgt, feat[(size_t)s * HC + t], acc);
  }
  float o = acc / den + bias[t];
  if (do_relu) o = fmaxf(o, 0.f);
  out[(size_t)n * HC + t] = o;
}

// ---------------------------------------------------------------------------
extern "C" void kernel_launch(void* const* d_in, const int* in_sizes, int n_in,
                              void* d_out, int out_size, void* d_ws, size_t ws_size,
                              hipStream_t stream) {
  const float* x        = (const float*)d_in[0];
  const int*   ei       = (const int*)d_in[1];   // int64 inputs arrive as int32
  const float* w_ih0    = (const float*)d_in[2];
  const float* w_hh0    = (const float*)d_in[3];
  const float* b_ih0    = (const float*)d_in[4];
  const float* b_hh0    = (const float*)d_in[5];
  const float* w_ih1    = (const float*)d_in[6];
  const float* w_hh1    = (const float*)d_in[7];
  const float* b_ih1    = (const float*)d_in[8];
  const float* b_hh1    = (const float*)d_in[9];
  const float* W1       = (const float*)d_in[10];
  const float* att_src1 = (const float*)d_in[11];
  const float* att_dst1 = (const float*)d_in[12];
  const float* bias1    = (const float*)d_in[13];
  const float* W2       = (const float*)d_in[14];
  const float* att_src2 = (const float*)d_in[15];
  const float* att_dst2 = (const float*)d_in[16];
  const float* bias2    = (const float*)d_in[17];
  float* out = (float*)d_out;

  const int N = NN_;
  const int E = in_sizes[1] / 2;

  // ---- workspace layout with overlays (peak ~50.5 MB) ----
  // Region A (5.12M floats): gi [0,3.84M) + h0 [3.84M,5.12M); later hmm1 (all of A)
  // Region B (1.28M): h1
  // Region C (5.12M): g1o
  // Region D (0.64M): hmm2
  float* f    = (float*)d_ws;
  float* gi   = f;                         // in A
  float* h0   = f + (size_t)N * G3;        // in A (after gi)
  float* hmm1 = f;                         // = A, reused after h1 is produced
  float* h1   = f + (size_t)N * HC1;                    // B
  float* g1o  = h1 + (size_t)N * HID;                   // C
  float* hmm2 = g1o + (size_t)N * HC1;                  // D
  float* as1  = hmm2 + (size_t)N * OUTD;
  float* ad1  = as1 + (size_t)N * 4;
  float* as2  = ad1 + (size_t)N * 4;
  float* ad2  = as2 + (size_t)N;
  int* cnt    = (int*)(ad2 + (size_t)N);
  int* offs   = cnt + N;        // N+1
  int* cursor = offs + (N + 1);
  int* csr    = cursor + N;     // E

  const int mblocks = (N + 63) / 64;

  // GRU layer 0
  gemm_k<true><<<dim3(mblocks, G3 / 64), 256, 0, stream>>>(x, w_ih0, b_ih0, gi, N, G3, IND);
  gru_scan<<<1, G3, 0, stream>>>(gi, w_hh0, b_hh0, h0, N);
  // GRU layer 1
  gemm_k<true><<<dim3(mblocks, G3 / 64), 256, 0, stream>>>(h0, w_ih1, b_ih1, gi, N, G3, HID);
  gru_scan<<<1, G3, 0, stream>>>(gi, w_hh1, b_hh1, h1, N);

  // CSR by dst (shared by both GAT layers)
  hipMemsetAsync(cnt, 0, (size_t)N * sizeof(int), stream);
  edge_count<<<(E + 255) / 256, 256, 0, stream>>>(ei, cnt, E);
  prefix_scan<<<1, 1024, 0, stream>>>(cnt, offs, cursor, N);
  edge_fill<<<(E + 255) / 256, 256, 0, stream>>>(ei, cursor, csr, E);

  // GAT layer 1: feat transform (overwrites A; reads h1 in B) + attention + aggregate
  gemm_k<false><<<dim3(mblocks, HC1 / 64), 256, 0, stream>>>(h1, W1, nullptr, hmm1, N, HC1, HID);
  att_dots<<<N, 4 * 64, 0, stream>>>(hmm1, att_src1, att_dst1, as1, ad1, 4, HID);
  gat_agg<<<N, HC1, 0, stream>>>(hmm1, as1, ad1, offs, csr, bias1, g1o, 4, 7, 1);

  // GAT layer 2
  gemm_k<false><<<dim3(mblocks, OUTD / 64), 256, 0, stream>>>(g1o, W2, nullptr, hmm2, N, OUTD, HC1);
  att_dots<<<N, 1 * 64, 0, stream>>>(hmm2, att_src2, att_dst2, as2, ad2, 1, OUTD);
  gat_agg<<<N, OUTD, 0, stream>>>(hmm2, as2, ad2, offs, csr, bias2, out, 1, 6, 0);
}

// Round 3
// 12905.107 us; speedup vs baseline: 2.2564x; 2.2564x over previous
//
#include <hip/hip_runtime.h>
#include <math.h>

#define NN_  10000
#define NE_  320000
#define IND  64
#define HID  128
#define G3   384   // 3*HID
#define HC1  512   // 4 heads * 128
#define OUTD 64

typedef _Float16 h2f __attribute__((ext_vector_type(2)));
union UH4 { uint4 u; h2f h[4]; };

__device__ __forceinline__ float leakyf_(float x){ return x>0.f ? x : 0.2f*x; }
__device__ __forceinline__ float fsig_(float x){ return 1.f/(1.f+__expf(-x)); }
__device__ __forceinline__ float ftanh_(float x){ float e=__expf(2.f*x); return 1.f-2.f/(e+1.f); }

// ---------------------------------------------------------------------------
// Generic tiled fp32 GEMM.  C[m,n] = sum_k A[m,k] * (TB ? B[n,k] : B[k,n]) + bias[n]
// ---------------------------------------------------------------------------
template<bool TB>
__global__ __launch_bounds__(256) void gemm_k(const float* __restrict__ A,
                                              const float* __restrict__ B,
                                              const float* __restrict__ bias,
                                              float* __restrict__ C,
                                              int M, int N, int K) {
  __shared__ float As[16][65];
  __shared__ float Bs[16][65];
  const int bm = blockIdx.x * 64, bn = blockIdx.y * 64;
  const int tid = threadIdx.x;
  const int tm = (tid >> 4) << 2, tn = (tid & 15) << 2;
  float acc[4][4] = {};
  const int row = tid & 63, kq = (tid >> 6) << 2;
  for (int k0 = 0; k0 < K; k0 += 16) {
    float4 av = make_float4(0.f, 0.f, 0.f, 0.f);
    const int m = bm + row;
    if (m < M) av = *(const float4*)(A + (size_t)m * K + k0 + kq);
    As[kq + 0][row] = av.x; As[kq + 1][row] = av.y;
    As[kq + 2][row] = av.z; As[kq + 3][row] = av.w;
    if (TB) {
      float4 bv = *(const float4*)(B + (size_t)(bn + row) * K + k0 + kq);
      Bs[kq + 0][row] = bv.x; Bs[kq + 1][row] = bv.y;
      Bs[kq + 2][row] = bv.z; Bs[kq + 3][row] = bv.w;
    } else {
      const int kr = tid >> 4, nq = (tid & 15) << 2;
      float4 bv = *(const float4*)(B + (size_t)(k0 + kr) * N + bn + nq);
      Bs[kr][nq + 0] = bv.x; Bs[kr][nq + 1] = bv.y;
      Bs[kr][nq + 2] = bv.z; Bs[kr][nq + 3] = bv.w;
    }
    __syncthreads();
#pragma unroll
    for (int kk = 0; kk < 16; kk++) {
      float a[4], b[4];
#pragma unroll
      for (int i = 0; i < 4; i++) a[i] = As[kk][tm + i];
#pragma unroll
      for (int j = 0; j < 4; j++) b[j] = Bs[kk][tn + j];
#pragma unroll
      for (int i = 0; i < 4; i++)
#pragma unroll
        for (int j = 0; j < 4; j++) acc[i][j] = fmaf(a[i], b[j], acc[i][j]);
    }
    __syncthreads();
  }
#pragma unroll
  for (int i = 0; i < 4; i++) {
    const int m = bm + tm + i;
    if (m < M) {
#pragma unroll
      for (int j = 0; j < 4; j++) {
        const int n = bn + tn + j;
        float v = acc[i][j];
        if (bias) v += bias[n];
        C[(size_t)m * N + n] = v;
      }
    }
  }
}

// ---------------------------------------------------------------------------
// GRU scan, one layer.  Single block, 128 threads (2 waves).  Thread j owns
// the THREE gate rows (r=j, z=j+128, n=j+256) of w_hh as packed fp16 in
// registers (192 VGPRs) and computes gates entirely locally via
// v_dot2_f32_f16.  h is broadcast through LDS as packed fp16 (256 B),
// double-buffered -> ONE barrier per step.  gi prefetched 2 steps ahead.
// ---------------------------------------------------------------------------
__global__ __launch_bounds__(128, 1) void gru_scan(const float* __restrict__ gi,
                                                   const float* __restrict__ w_hh,
                                                   const float* __restrict__ b_hh,
                                                   float* __restrict__ h_out,
                                                   int T) {
  __shared__ h2f hbuf[2][HID / 2];   // packed fp16 h, double-buffered
  const int j = threadIdx.x;

  // load + convert the 3 weight rows to packed fp16 registers
  h2f wr[64], wz[64], wn[64];
#pragma unroll
  for (int i = 0; i < 32; i++) {
    float4 a = *(const float4*)(w_hh + (size_t)j * HID + i * 4);
    wr[2 * i]     = h2f{(_Float16)a.x, (_Float16)a.y};
    wr[2 * i + 1] = h2f{(_Float16)a.z, (_Float16)a.w};
  }
#pragma unroll
  for (int i = 0; i < 32; i++) {
    float4 a = *(const float4*)(w_hh + (size_t)(j + HID) * HID + i * 4);
    wz[2 * i]     = h2f{(_Float16)a.x, (_Float16)a.y};
    wz[2 * i + 1] = h2f{(_Float16)a.z, (_Float16)a.w};
  }
#pragma unroll
  for (int i = 0; i < 32; i++) {
    float4 a = *(const float4*)(w_hh + (size_t)(j + 2 * HID) * HID + i * 4);
    wn[2 * i]     = h2f{(_Float16)a.x, (_Float16)a.y};
    wn[2 * i + 1] = h2f{(_Float16)a.z, (_Float16)a.w};
  }
  const float bhr = b_hh[j];
  const float bhz = b_hh[j + HID];
  const float bhn = b_hh[j + 2 * HID];

  float hcur = 0.f;
  ((_Float16*)hbuf[0])[j] = (_Float16)0.f;
  __syncthreads();

  // gi prefetch pipeline (2 steps ahead)
  float3 g0, g1;
  {
    const float* gp = gi + j;
    g0.x = gp[0]; g0.y = gp[HID]; g0.z = gp[2 * HID];
    gp = gi + G3 + j;
    g1.x = gp[0]; g1.y = gp[HID]; g1.z = gp[2 * HID];
  }

  auto do_step = [&](int t, float3 g, int p) -> float3 {
    // prefetch gi for t+2 (issued before the dot loop; consumed 2 steps later)
    const int tp = (t + 2 < T) ? (t + 2) : (T - 1);
    const float* gp = gi + (size_t)tp * G3 + j;
    float3 nx;
    nx.x = gp[0]; nx.y = gp[HID]; nx.z = gp[2 * HID];

    // broadcast-read h (packed fp16, 256 B) from LDS
    uint4 hv[16];
    const uint4* hp = (const uint4*)hbuf[p];
#pragma unroll
    for (int i = 0; i < 16; i++) hv[i] = hp[i];

    // three 128-length dots via v_dot2_f32_f16, 2 accumulators each for ILP
    float ar0 = bhr, ar1 = 0.f, az0 = bhz, az1 = 0.f, an0 = bhn, an1 = 0.f;
#pragma unroll
    for (int i = 0; i < 16; i++) {
      UH4 u; u.u = hv[i];
#pragma unroll
      for (int q = 0; q < 4; q++) {
        const int k = i * 4 + q;
        const h2f hh = u.h[q];
        if (k & 1) {
          ar1 = __builtin_amdgcn_fdot2(wr[k], hh, ar1, false);
          az1 = __builtin_amdgcn_fdot2(wz[k], hh, az1, false);
          an1 = __builtin_amdgcn_fdot2(wn[k], hh, an1, false);
        } else {
          ar0 = __builtin_amdgcn_fdot2(wr[k], hh, ar0, false);
          az0 = __builtin_amdgcn_fdot2(wz[k], hh, az0, false);
          an0 = __builtin_amdgcn_fdot2(wn[k], hh, an0, false);
        }
      }
    }
    const float r = fsig_(g.x + ar0 + ar1);
    const float z = fsig_(g.y + az0 + az1);
    const float n = ftanh_(g.z + r * (an0 + an1));
    hcur = (1.f - z) * n + z * hcur;

    ((_Float16*)hbuf[p ^ 1])[j] = (_Float16)hcur;
    __syncthreads();
    h_out[(size_t)t * HID + j] = hcur;
    return nx;
  };

  for (int t = 0; t < T; t += 2) {
    g0 = do_step(t, g0, 0);
    g1 = do_step(t + 1, g1, 1);
  }
}

// ---------------------------------------------------------------------------
// Attention per-node dots: a_s[n,h] = feat[n,h,:].att_src[h,:]  (same for dst)
// ---------------------------------------------------------------------------
__global__ void att_dots(const float* __restrict__ feat,
                         const float* __restrict__ att_src,
                         const float* __restrict__ att_dst,
                         float* __restrict__ a_s, float* __restrict__ a_d,
                         int heads, int C) {
  const int n = blockIdx.x;
  const int h = threadIdx.x >> 6;
  const int lane = threadIdx.x & 63;
  float ss = 0.f, dd = 0.f;
  const float* f = feat + (size_t)n * heads * C + h * C;
  for (int c = lane; c < C; c += 64) {
    const float v = f[c];
    ss = fmaf(v, att_src[h * C + c], ss);
    dd = fmaf(v, att_dst[h * C + c], dd);
  }
#pragma unroll
  for (int o = 32; o > 0; o >>= 1) {
    ss += __shfl_down(ss, o);
    dd += __shfl_down(dd, o);
  }
  if (lane == 0) { a_s[n * heads + h] = ss; a_d[n * heads + h] = dd; }
}

// ---------------------------------------------------------------------------
// CSR build (edge_index arrives as int32: ei[0..E) = src, ei[E..2E) = dst)
// ---------------------------------------------------------------------------
__global__ void edge_count(const int* __restrict__ ei, int* __restrict__ cnt, int E) {
  const int e = blockIdx.x * 256 + threadIdx.x;
  if (e < E) atomicAdd(&cnt[ei[E + e]], 1);
}

__global__ __launch_bounds__(1024) void prefix_scan(const int* __restrict__ cnt,
                                                    int* __restrict__ offs,
                                                    int* __restrict__ cursor, int N) {
  __shared__ int buf[1024];
  __shared__ int carry;
  const int tid = threadIdx.x;
  if (tid == 0) carry = 0;
  __syncthreads();
  for (int base = 0; base < N; base += 1024) {
    const int i = base + tid;
    const int v = (i < N) ? cnt[i] : 0;
    buf[tid] = v;
    __syncthreads();
    for (int d = 1; d < 1024; d <<= 1) {
      int t = 0;
      if (tid >= d) t = buf[tid - d];
      __syncthreads();
      buf[tid] += t;
      __syncthreads();
    }
    const int incl = buf[tid] + carry;
    if (i < N) { offs[i] = incl - v; cursor[i] = incl - v; }
    __syncthreads();
    if (tid == 1023) carry = incl;
    __syncthreads();
  }
  if (tid == 0) offs[N] = carry;
}

__global__ void edge_fill(const int* __restrict__ ei, int* __restrict__ cursor,
                          int* __restrict__ csr, int E) {
  const int e = blockIdx.x * 256 + threadIdx.x;
  if (e < E) {
    const int d = ei[E + e];
    const int s = ei[e];
    const int pos = atomicAdd(&cursor[d], 1);
    csr[pos] = s;
  }
}

// ---------------------------------------------------------------------------
// GAT softmax-aggregation.  One block per dst node; blockDim = heads<<cshift.
// ---------------------------------------------------------------------------
__global__ void gat_agg(const float* __restrict__ feat,
                        const float* __restrict__ a_s, const float* __restrict__ a_d,
                        const int* __restrict__ offs, const int* __restrict__ csr,
                        const float* __restrict__ bias, float* __restrict__ out,
                        int heads, int cshift, int do_relu) {
  const int n = blockIdx.x;
  const int t = threadIdx.x;
  const int HC = blockDim.x;
  const int h = t >> cshift;
  const int beg = offs[n], end = offs[n + 1];
  const float ad = a_d[n * heads + h];
  const float self_e = leakyf_(a_s[n * heads + h] + ad);
  float m = self_e;
  for (int i = beg; i < end; i++) {
    const int s = csr[i];
    m = fmaxf(m, leakyf_(a_s[s * heads + h] + ad));
  }
  float den = expf(self_e - m);
  float acc = den * feat[(size_t)n * HC + t];
  for (int i = beg; i < end; i++) {
    const int s = csr[i];
    const float wgt = expf(leakyf_(a_s[s * heads + h] + ad) - m);
    den += wgt;
    acc = fmaf(wgt, feat[(size_t)s * HC + t], acc);
  }
  float o = acc / den + bias[t];
  if (do_relu) o = fmaxf(o, 0.f);
  out[(size_t)n * HC + t] = o;
}

// ---------------------------------------------------------------------------
extern "C" void kernel_launch(void* const* d_in, const int* in_sizes, int n_in,
                              void* d_out, int out_size, void* d_ws, size_t ws_size,
                              hipStream_t stream) {
  const float* x        = (const float*)d_in[0];
  const int*   ei       = (const int*)d_in[1];   // int64 inputs arrive as int32
  const float* w_ih0    = (const float*)d_in[2];
  const float* w_hh0    = (const float*)d_in[3];
  const float* b_ih0    = (const float*)d_in[4];
  const float* b_hh0    = (const float*)d_in[5];
  const float* w_ih1    = (const float*)d_in[6];
  const float* w_hh1    = (const float*)d_in[7];
  const float* b_ih1    = (const float*)d_in[8];
  const float* b_hh1    = (const float*)d_in[9];
  const float* W1       = (const float*)d_in[10];
  const float* att_src1 = (const float*)d_in[11];
  const float* att_dst1 = (const float*)d_in[12];
  const float* bias1    = (const float*)d_in[13];
  const float* W2       = (const float*)d_in[14];
  const float* att_src2 = (const float*)d_in[15];
  const float* att_dst2 = (const float*)d_in[16];
  const float* bias2    = (const float*)d_in[17];
  float* out = (float*)d_out;

  const int N = NN_;
  const int E = in_sizes[1] / 2;

  // ---- workspace layout with overlays (peak ~50.5 MB) ----
  float* f    = (float*)d_ws;
  float* gi   = f;                         // region A
  float* h0   = f + (size_t)N * G3;        // region A (after gi)
  float* hmm1 = f;                         // = A, reused after h1 is produced
  float* h1   = f + (size_t)N * HC1;                    // B
  float* g1o  = h1 + (size_t)N * HID;                   // C
  float* hmm2 = g1o + (size_t)N * HC1;                  // D
  float* as1  = hmm2 + (size_t)N * OUTD;
  float* ad1  = as1 + (size_t)N * 4;
  float* as2  = ad1 + (size_t)N * 4;
  float* ad2  = as2 + (size_t)N;
  int* cnt    = (int*)(ad2 + (size_t)N);
  int* offs   = cnt + N;        // N+1
  int* cursor = offs + (N + 1);
  int* csr    = cursor + N;     // E

  const int mblocks = (N + 63) / 64;

  // GRU layer 0
  gemm_k<true><<<dim3(mblocks, G3 / 64), 256, 0, stream>>>(x, w_ih0, b_ih0, gi, N, G3, IND);
  gru_scan<<<1, HID, 0, stream>>>(gi, w_hh0, b_hh0, h0, N);
  // GRU layer 1
  gemm_k<true><<<dim3(mblocks, G3 / 64), 256, 0, stream>>>(h0, w_ih1, b_ih1, gi, N, G3, HID);
  gru_scan<<<1, HID, 0, stream>>>(gi, w_hh1, b_hh1, h1, N);

  // CSR by dst (shared by both GAT layers)
  hipMemsetAsync(cnt, 0, (size_t)N * sizeof(int), stream);
  edge_count<<<(E + 255) / 256, 256, 0, stream>>>(ei, cnt, E);
  prefix_scan<<<1, 1024, 0, stream>>>(cnt, offs, cursor, N);
  edge_fill<<<(E + 255) / 256, 256, 0, stream>>>(ei, cursor, csr, E);

  // GAT layer 1
  gemm_k<false><<<dim3(mblocks, HC1 / 64), 256, 0, stream>>>(h1, W1, nullptr, hmm1, N, HC1, HID);
  att_dots<<<N, 4 * 64, 0, stream>>>(hmm1, att_src1, att_dst1, as1, ad1, 4, HID);
  gat_agg<<<N, HC1, 0, stream>>>(hmm1, as1, ad1, offs, csr, bias1, g1o, 4, 7, 1);

  // GAT layer 2
  gemm_k<false><<<dim3(mblocks, OUTD / 64), 256, 0, stream>>>(g1o, W2, nullptr, hmm2, N, OUTD, HC1);
  att_dots<<<N, 1 * 64, 0, stream>>>(hmm2, att_src2, att_dst2, as2, ad2, 1, OUTD);
  gat_agg<<<N, OUTD, 0, stream>>>(hmm2, as2, ad2, offs, csr, bias2, out, 1, 6, 0);
}